// Round 9
// baseline (449.538 us; speedup 1.0000x reference)
//
#include <hip/hip_runtime.h>

#define E_TOTAL 600000
#define N_NODES 50000
#define NBUCK 1563          // src>>5 buckets (49999>>5 = 1562)
#define EB 3                // tiles per edge block
#define NEB 3125            // edge blocks: 3125 * 3 * 64 = 600000 exact
#define NNT 782             // node tiles (64 nodes each)
#define SCAT_B 2344         // scatter blocks: 2344*256 >= 600000
#define LDS_X 136           // node-kernel x-stage row stride (shorts)
#define LDP 264             // pack/hidden row stride (shorts), 528B

typedef __attribute__((ext_vector_type(8))) short short8;
typedef __attribute__((ext_vector_type(8))) _Float16 half8;
typedef __attribute__((ext_vector_type(4))) float f32x4;

__device__ __forceinline__ unsigned f2bf_u(float f) {
  union { float f; unsigned u; } v; v.f = f;
  return (v.u + 0x7fffu + ((v.u >> 16) & 1u)) >> 16;  // RNE
}
__device__ __forceinline__ unsigned short f2h_u(float f) {
  union { _Float16 h; unsigned short u; } v; v.h = (_Float16)f;
  return v.u;
}
// LDS-only barrier: drain ds ops, do NOT drain vmcnt (prefetch stays in flight).
__device__ __forceinline__ void ldsBarrier() {
  asm volatile("s_waitcnt lgkmcnt(0)\n\ts_barrier" ::: "memory");
}

// ---- K1: weight prep (blocks 0..80) || src-bucket histogram (blocks 81+) ----
__global__ __launch_bounds__(256) void prep_hist(
    const float* __restrict__ W1, const float* __restrict__ W2,
    const float* __restrict__ b1, const int* __restrict__ ei,
    unsigned short* __restrict__ W1c, unsigned short* __restrict__ W2t2,
    unsigned short* __restrict__ b1h, int* __restrict__ hist) {
  __shared__ float t[32][33];
  int bid = blockIdx.x;
  if (bid >= 81) {
    int e = (bid - 81) * 256 + threadIdx.x;
    if (e < E_TOTAL) atomicAdd(&hist[ei[e] >> 5], 1);
    return;
  }
  int tx = threadIdx.x & 31, ty = threadIdx.x >> 5;
  if (bid < 64) {
    int k0 = (bid >> 3) * 32, n0 = (bid & 7) * 32;
#pragma unroll
    for (int i = 0; i < 32; i += 8) t[ty + i][tx] = W1[(k0 + ty + i) * 256 + n0 + tx];
    __syncthreads();
    int coff = (k0 >= 128) ? 256 : 0;
#pragma unroll
    for (int i = 0; i < 32; i += 8)
      W1c[(n0 + ty + i + coff) * 128 + (k0 & 127) + tx] = (unsigned short)f2bf_u(t[tx][ty + i]);
  } else if (bid < 80) {
    int b = bid - 64;
    int k0 = (b >> 1) * 32, n0 = (b & 1) * 32;
#pragma unroll
    for (int i = 0; i < 32; i += 8) t[ty + i][tx] = W2[(k0 + ty + i) * 64 + n0 + tx];
    __syncthreads();
#pragma unroll
    for (int i = 0; i < 32; i += 8)
      W2t2[(n0 + ty + i) * 256 + k0 + tx] = f2h_u(t[tx][ty + i]);
  } else {
    b1h[threadIdx.x] = f2h_u(b1[threadIdx.x]);
  }
}

// ---- K2: single-block exclusive scan over 1563 bucket counts (7 per thread) ----
__global__ __launch_bounds__(256) void bscan(const int* __restrict__ hist,
                                             int* __restrict__ offs) {
  __shared__ int tmp[256];
  const int t = threadIdx.x;
  const int base = t * 7;
  int loc[7];
  int s = 0;
#pragma unroll
  for (int i = 0; i < 7; ++i) {
    int idx = base + i;
    int v = (idx < NBUCK) ? hist[idx] : 0;
    loc[i] = s; s += v;
  }
  tmp[t] = s; __syncthreads();
  for (int o = 1; o < 256; o <<= 1) {
    int u = (t >= o) ? tmp[t - o] : 0;
    __syncthreads();
    tmp[t] += u;
    __syncthreads();
  }
  int pre = tmp[t] - s;  // exclusive
#pragma unroll
  for (int i = 0; i < 7; ++i) {
    int idx = base + i;
    if (idx < NBUCK) offs[idx] = pre + loc[i];
  }
}

// ---- K3: edge scatter (blocks 0..2343, 8B packed payload) || node_uv (rest) ----
// sorted[p] = { src | dst<<16 , original edge id }  (src,dst < 2^16)
__global__ __launch_bounds__(256, 3) void scat_node(
    const int* __restrict__ ei, int* __restrict__ offs, uint2* __restrict__ sorted,
    const float* __restrict__ x, const unsigned short* __restrict__ W1c,
    unsigned short* __restrict__ U, unsigned short* __restrict__ V) {
  const int tid = threadIdx.x;
  int bid = blockIdx.x;
  if (bid < SCAT_B) {
    int e = bid * 256 + tid;
    if (e < E_TOTAL) {
      int s = ei[e], d = ei[E_TOTAL + e];
      int p = atomicAdd(&offs[s >> 5], 1);
      sorted[p] = make_uint2((unsigned)s | ((unsigned)d << 16), (unsigned)e);
    }
    return;
  }
  // ---- node part: U[n][256] = x@W1[:128]; V[n][256] = x@W1[128:] (f16) ----
  __shared__ __align__(16) unsigned short xt[64 * LDP];
  bid -= SCAT_B;
  const int ntile = bid >> 1, chalf = bid & 1;
  const int n0 = ntile * 64;
  const int lane = tid & 63, w = tid >> 6, m = lane & 15, q = lane >> 4;

  const int kb = (tid & 15) * 8;
  const int r0 = tid >> 4;
#pragma unroll
  for (int i = 0; i < 4; ++i) {
    int r = r0 + 16 * i;
    int n = n0 + r; if (n >= N_NODES) n = N_NODES - 1;
    const float* p = x + (size_t)n * 128 + kb;
    f32x4 g0 = *(const f32x4*)p, g1 = *(const f32x4*)(p + 4);
    short8 s;
#pragma unroll
    for (int j = 0; j < 4; ++j) { s[j] = (short)f2bf_u(g0[j]); s[4 + j] = (short)f2bf_u(g1[j]); }
    *(short8*)&xt[r * LDS_X + kb] = s;
  }

  int w1o[4];
#pragma unroll
  for (int nt = 0; nt < 4; ++nt) w1o[nt] = (chalf * 256 + (w * 4 + nt) * 16 + m) * 128 + q * 8;
  short8 wa[2][4];
#pragma unroll
  for (int nt = 0; nt < 4; ++nt) wa[0][nt] = *(const short8*)&W1c[w1o[nt]];

  __syncthreads();

  f32x4 acc[4][4];
#pragma unroll
  for (int nt = 0; nt < 4; ++nt)
#pragma unroll
    for (int mt = 0; mt < 4; ++mt) acc[nt][mt] = (f32x4){0.f, 0.f, 0.f, 0.f};

#pragma unroll
  for (int kk = 0; kk < 4; ++kk) {
    const int cur = kk & 1, nx = cur ^ 1;
    if (kk < 3) {
#pragma unroll
      for (int nt = 0; nt < 4; ++nt) wa[nx][nt] = *(const short8*)&W1c[w1o[nt] + (kk + 1) * 32];
    }
    short8 f[4];
#pragma unroll
    for (int mt = 0; mt < 4; ++mt)
      f[mt] = *(const short8*)&xt[(mt * 16 + m) * LDS_X + kk * 32 + q * 8];
#pragma unroll
    for (int nt = 0; nt < 4; ++nt)
#pragma unroll
      for (int mt = 0; mt < 4; ++mt)
        acc[nt][mt] = __builtin_amdgcn_mfma_f32_16x16x32_bf16(wa[cur][nt], f[mt], acc[nt][mt], 0, 0, 0);
  }

  __syncthreads();

#pragma unroll
  for (int nt = 0; nt < 4; ++nt)
#pragma unroll
    for (int mt = 0; mt < 4; ++mt) {
      union { _Float16 h[4]; uint2 u; } pk;
#pragma unroll
      for (int r = 0; r < 4; ++r) pk.h[r] = (_Float16)acc[nt][mt][r];
      *(uint2*)&xt[(mt * 16 + m) * LDP + (w * 4 + nt) * 16 + q * 4] = pk.u;
    }

  __syncthreads();

  const int rr = tid >> 2, c8 = tid & 3;
  if (n0 + rr < N_NODES) {
    unsigned short* dst = (chalf ? V : U) + (size_t)(n0 + rr) * 256;
#pragma unroll
    for (int i = 0; i < 8; ++i) {
      int ch = c8 + 4 * i;
      *(short8*)&dst[ch * 8] = *(const short8*)&xt[rr * LDP + ch * 8];
    }
  }
}

// ---- K4: edge kernel. 3 tiles/block, cross-tile register prefetch of the
// u/v gather (in flight under MFMA+stores); bucket-sorted order keeps the
// u-window 16KB/tile; out scattered by original edge id ----
__global__ __launch_bounds__(256, 3) void edge_mlp(
    const unsigned short* __restrict__ U, const unsigned short* __restrict__ V,
    const uint2* __restrict__ sorted,
    const unsigned short* __restrict__ W2t2, const unsigned short* __restrict__ b1h,
    const float* __restrict__ b2, float* __restrict__ out) {
  __shared__ __align__(16) unsigned short hid[64 * LDP];
  const int tid = threadIdx.x;
  const int lane = tid & 63, w = tid >> 6, m = lane & 15, q = lane >> 4;
  const int c = tid & 31;    // 16B chunk (k-dims c*8..c*8+8)
  const int e0 = tid >> 5;   // 0..7

  half8 w2r[8];
  const int w2off = (w * 16 + m) * 256 + q * 8;
#pragma unroll
  for (int kk = 0; kk < 8; ++kk) w2r[kk] = *(const half8*)&W2t2[w2off + kk * 32];
  half8 bias = *(const half8*)&b1h[c * 8];
  f32x4 b2v = *(const f32x4*)&b2[w * 16 + q * 4];

  const int base = blockIdx.x * (EB * 64);

  // prologue: issue tile-0 gathers (16 loads, 64 VGPR in flight)
  half8 gu[8], gv[8];
#pragma unroll
  for (int i = 0; i < 8; ++i) {
    uint2 s8 = sorted[base + e0 + 8 * i];
    gu[i] = *(const half8*)&U[(size_t)(s8.x & 0xFFFFu) * 256 + c * 8];
    gv[i] = *(const half8*)&V[(size_t)(s8.x >> 16) * 256 + c * 8];
  }

  for (int j = 0; j < EB; ++j) {
    const int tb = base + j * 64;

    // consume prefetched regs: relu(u+v+b1) -> hid
#pragma unroll
    for (int i = 0; i < 8; ++i) {
      half8 s = gu[i] + gv[i] + bias;   // v_pk_add_f16 x8
#pragma unroll
      for (int jj = 0; jj < 8; ++jj) s[jj] = s[jj] > (_Float16)0 ? s[jj] : (_Float16)0;
      *(half8*)&hid[(e0 + 8 * i) * LDP + c * 8] = s;
    }

    // issue next tile's gathers; they stay in flight across MFMA + stores
    if (j + 1 < EB) {
      const int nb = tb + 64;
#pragma unroll
      for (int i = 0; i < 8; ++i) {
        uint2 s8 = sorted[nb + e0 + 8 * i];
        gu[i] = *(const half8*)&U[(size_t)(s8.x & 0xFFFFu) * 256 + c * 8];
        gv[i] = *(const half8*)&V[(size_t)(s8.x >> 16) * 256 + c * 8];
      }
    }

    ldsBarrier();  // hid visible (vmcnt NOT drained)

    f32x4 acc2[4];
#pragma unroll
    for (int mt = 0; mt < 4; ++mt) acc2[mt] = (f32x4){0.f, 0.f, 0.f, 0.f};
#pragma unroll
    for (int kk = 0; kk < 8; ++kk) {
#pragma unroll
      for (int mt = 0; mt < 4; ++mt) {
        half8 h = *(const half8*)&hid[(mt * 16 + m) * LDP + kk * 32 + q * 8];
        acc2[mt] = __builtin_amdgcn_mfma_f32_16x16x32_f16(w2r[kk], h, acc2[mt], 0, 0, 0);
      }
    }

#pragma unroll
    for (int mt = 0; mt < 4; ++mt) {
      unsigned eo = sorted[tb + mt * 16 + m].y;  // original edge id
      f32x4 o;
#pragma unroll
      for (int r = 0; r < 4; ++r) o[r] = acc2[mt][r] + b2v[r];
      __builtin_nontemporal_store(o, (f32x4*)&out[(size_t)eo * 64 + w * 16 + q * 4]);
    }

    ldsBarrier();  // hid reads done on all waves before next overwrite
  }
}

extern "C" void kernel_launch(void* const* d_in, const int* in_sizes, int n_in,
                              void* d_out, int out_size, void* d_ws, size_t ws_size,
                              hipStream_t stream) {
  const float* x  = (const float*)d_in[0];
  const int*   ei = (const int*)d_in[1];
  const float* W1 = (const float*)d_in[2];
  const float* b1 = (const float*)d_in[3];
  const float* W2 = (const float*)d_in[4];
  const float* b2 = (const float*)d_in[5];
  float* out = (float*)d_out;

  unsigned short* W1c  = (unsigned short*)d_ws;      // [512][128] bf16
  unsigned short* W2t2 = W1c + 512 * 128;            // [64][256] f16
  unsigned short* b1h  = W2t2 + 64 * 256;            // [256] f16
  unsigned short* U    = b1h + 256;                  // [50000][256] f16 (25.6 MB)
  unsigned short* V    = U + (size_t)N_NODES * 256;  // [50000][256] f16 (25.6 MB)
  int*   hist   = (int*)(V + (size_t)N_NODES * 256); // [1563]
  int*   offs   = hist + NBUCK;                      // [1563]
  uint2* sorted = (uint2*)(offs + NBUCK);            // [600000] 8B packed

  hipMemsetAsync(hist, 0, NBUCK * sizeof(int), stream);
  prep_hist<<<81 + SCAT_B, 256, 0, stream>>>(W1, W2, b1, ei, W1c, W2t2, b1h, hist);
  bscan<<<1, 256, 0, stream>>>(hist, offs);
  scat_node<<<SCAT_B + NNT * 2, 256, 0, stream>>>(ei, offs, sorted, x, W1c, U, V);
  edge_mlp<<<NEB, 256, 0, stream>>>(U, V, sorted, W2t2, b1h, b2, out);
}